// Round 6
// baseline (411.077 us; speedup 1.0000x reference)
//
#include <hip/hip_runtime.h>

#define N_GRAPHS 100000
#define NTYPES 8
#define MAXD 128
#define FEAT 256
#define NBLK 768           // 256 CUs x 3 blocks/CU, all resident from t=0
#define LDA 524            // LDS row stride in shorts

typedef __attribute__((ext_vector_type(8))) short short8;
typedef __attribute__((ext_vector_type(4))) float f32x4;
typedef __attribute__((ext_vector_type(4))) unsigned uint4v;

// dims {16,32,64,128,64,32,16,128}; KS = ceil(dim/32); OFFC = col offset (shorts)
constexpr int KSN[NTYPES]  = {1, 1, 2, 4, 2, 1, 1, 4};
constexpr int OFFC[NTYPES] = {0, 32, 64, 128, 256, 320, 352, 384};

__device__ __forceinline__ unsigned f2bf_u(float f) {
    unsigned u = __builtin_bit_cast(unsigned, f);
    return (u + 0x7fffu + ((u >> 16) & 1u)) >> 16;   // round-to-nearest-even
}
__device__ __forceinline__ unsigned cvt2(float lo, float hi) {
    return f2bf_u(lo) | (f2bf_u(hi) << 16);
}
__device__ __forceinline__ short8 cvt8(f32x4 a, f32x4 b) {
    uint4v u;
    u.x = cvt2(a.x, a.y); u.y = cvt2(a.z, a.w);
    u.z = cvt2(b.x, b.y); u.w = cvt2(b.z, b.w);
    return __builtin_bit_cast(short8, u);
}

// --- W -> bf16 fragment prepack. wp[(((t*16 + ct)*4 + ks)*4 + cgrp)*16 + c16]
//     = W[t][ct*16 + c16][ks*32 + cgrp*8 .. +7], zero-masked at k >= dim. 512 KB.
__global__ __launch_bounds__(256)
void prepack_w(const float* __restrict__ W, short8* __restrict__ wp)
{
    const int idx  = blockIdx.x * 256 + threadIdx.x;   // 32768
    const int c16  = idx & 15;
    const int cgrp = (idx >> 4) & 3;
    const int ks   = (idx >> 6) & 3;
    const int ct   = (idx >> 8) & 15;
    const int t    = (idx >> 12) & 7;
    const int col  = ct * 16 + c16;
    const int k    = ks * 32 + cgrp * 8;
    const int dim  = 16 << ((0x30123210u >> (4 * t)) & 0xf);
    const float* src = W + ((size_t)t * FEAT + col) * MAXD + k;
    f32x4 a = *(const f32x4*)src;
    f32x4 b = *(const f32x4*)(src + 4);
    #pragma unroll
    for (int j = 0; j < 4; ++j) {
        if (k + j     >= dim) a[j] = 0.f;
        if (k + 4 + j >= dim) b[j] = 0.f;
    }
    wp[idx] = cvt8(a, b);
}

// --- stage one 16-graph subtile: 16 rows x 512 concat-cols, f32->bf16->LDS.
// 256 threads: each thread stages 4 rows x one 8-float segment.
__device__ __forceinline__ void stage16(const float* __restrict__ x, int gs,
                                        unsigned short (* __restrict__ As)[LDA], int tid)
{
    const int c8 = tid & 63;       // segment index within 512-col concat row
    const int t = (c8 >= 4) + (c8 >= 8) + (c8 >= 16) + (c8 >= 32) +
                  (c8 >= 40) + (c8 >= 44) + (c8 >= 48);
    const int off8 = c8 < 4 ? 0 : c8 < 8 ? 4 : c8 < 16 ? 8 : c8 < 32 ? 16 :
                     c8 < 40 ? 32 : c8 < 44 ? 40 : c8 < 48 ? 44 : 48;
    const int k8 = c8 - off8;
    #pragma unroll
    for (int p = 0; p < 4; ++p) {
        const int row = p * 4 + (tid >> 6);
        int g = gs + row;
        if (g > N_GRAPHS - 1) g = N_GRAPHS - 1;   // clamp; stores are range-masked
        const float* rp = x + ((size_t)g * NTYPES + t) * MAXD + k8 * 8;
        f32x4 v0 = __builtin_nontemporal_load((const f32x4*)rp);
        f32x4 v1 = __builtin_nontemporal_load((const f32x4*)rp + 1);
        *(short8*)&As[row][c8 * 8] = cvt8(v0, v1);
    }
}

template<int T, bool PRE, bool FULL>
__device__ __forceinline__ void compute_types(const short8* __restrict__ wp,
                                              const float* __restrict__ W,
                                              const float* __restrict__ bias_g,
                                              const unsigned short (* __restrict__ A)[LDA],
                                              float* __restrict__ out,
                                              int gs, int gend,
                                              int wave, int cgrp, int c16)
{
    constexpr int KS = KSN[T];
    short8 Bf[KS][4];
    float  bias[4];
    #pragma unroll
    for (int nt = 0; nt < 4; ++nt) {
        bias[nt] = bias_g[T * FEAT + wave * 64 + nt * 16 + c16];
        if constexpr (PRE) {
            #pragma unroll
            for (int ks = 0; ks < KS; ++ks)
                Bf[ks][nt] = wp[(((T * 16 + wave * 4 + nt) * 4 + ks) * 4 + cgrp) * 16 + c16];
        } else {
            constexpr int DIM = (T==0||T==6) ? 16 : (T==1||T==5) ? 32 : (T==2||T==4) ? 64 : 128;
            const int col = wave * 64 + nt * 16 + c16;
            #pragma unroll
            for (int ks = 0; ks < KS; ++ks) {
                const int k = ks * 32 + cgrp * 8;
                const float* wf = W + ((size_t)T * FEAT + col) * MAXD + k;
                f32x4 a = *(const f32x4*)wf;
                f32x4 b = *(const f32x4*)(wf + 4);
                #pragma unroll
                for (int j = 0; j < 4; ++j) {
                    if (k + j     >= DIM) a[j] = 0.f;
                    if (k + 4 + j >= DIM) b[j] = 0.f;
                }
                Bf[ks][nt] = cvt8(a, b);
            }
        }
    }

    short8 a[KS];
    #pragma unroll
    for (int ks = 0; ks < KS; ++ks)
        a[ks] = *(const short8*)&A[c16][OFFC[T] + ks * 32 + cgrp * 8];

    f32x4 acc[4] = {{0,0,0,0},{0,0,0,0},{0,0,0,0},{0,0,0,0}};
    #pragma unroll
    for (int ks = 0; ks < KS; ++ks) {
        #pragma unroll
        for (int nt = 0; nt < 4; ++nt)
            acc[nt] = __builtin_amdgcn_mfma_f32_16x16x32_bf16(a[ks], Bf[ks][nt], acc[nt], 0, 0, 0);
    }

    #pragma unroll
    for (int nt = 0; nt < 4; ++nt) {
        const int col = wave * 64 + nt * 16 + c16;
        #pragma unroll
        for (int r = 0; r < 4; ++r) {
            const int g = gs + cgrp * 4 + r;   // C/D: row = cgrp*4 + reg (m89 layout)
            if (FULL || g < gend)
                __builtin_nontemporal_store(acc[nt][r] + bias[nt],
                    &out[((size_t)g * NTYPES + T) * FEAT + col]);
        }
    }

    if constexpr (T + 1 < NTYPES)
        compute_types<T + 1, PRE, FULL>(wp, W, bias_g, A, out, gs, gend, wave, cgrp, c16);
}

// Persistent: 768 blocks (3/CU, all resident), each owns a contiguous balanced
// graph range (~130 graphs = 9 subtiles of 16). Types inner per subtile ->
// dense 128 KB write regions. B fragments re-read per subtile from L2-hot wp
// (x/out are non-temporal so wp stays resident).
template<bool PRE>
__global__ __launch_bounds__(256, 3)
void node_enc(const float* __restrict__ x, const short8* __restrict__ wp,
              const float* __restrict__ W, const float* __restrict__ bias_g,
              float* __restrict__ out)
{
    __shared__ __align__(16) unsigned short As[2][16][LDA];
    const int tid  = threadIdx.x;
    const int lane = tid & 63;
    const int wave = tid >> 6;
    const int cgrp = lane >> 4;
    const int c16  = lane & 15;
    const long long b = blockIdx.x;
    const int gstart = (int)(b * N_GRAPHS / NBLK);
    const int gend   = (int)((b + 1) * N_GRAPHS / NBLK);
    const int ns     = (gend - gstart + 15) >> 4;   // 9 for every block

    stage16(x, gstart, As[0], tid);

    for (int s = 0; s < ns; ++s) {
        asm volatile("" ::: "memory");   // block LICM of Bf/bias loads across subtiles
        __syncthreads();                 // As[s&1] staged; prior reads of other buf done
        const int gs = gstart + s * 16;
        if (s + 1 < ns) stage16(x, gs + 16, As[(s + 1) & 1], tid);
        if (gs + 16 <= gend)
            compute_types<0, PRE, true >(wp, W, bias_g, As[s & 1], out, gs, gend, wave, cgrp, c16);
        else
            compute_types<0, PRE, false>(wp, W, bias_g, As[s & 1], out, gs, gend, wave, cgrp, c16);
    }
}

extern "C" void kernel_launch(void* const* d_in, const int* in_sizes, int n_in,
                              void* d_out, int out_size, void* d_ws, size_t ws_size,
                              hipStream_t stream)
{
    const float* x = (const float*)d_in[0];
    const float* W = (const float*)d_in[1];
    const float* b = (const float*)d_in[2];
    float* out = (float*)d_out;

    const size_t wp_bytes = (size_t)32768 * sizeof(short8);   // 512 KB

    if (ws_size >= wp_bytes) {
        short8* wp = (short8*)d_ws;
        prepack_w<<<128, 256, 0, stream>>>(W, wp);
        node_enc<true><<<NBLK, 256, 0, stream>>>(x, wp, W, b, out);
    } else {
        node_enc<false><<<NBLK, 256, 0, stream>>>(x, nullptr, W, b, out);
    }
}